// Round 1
// baseline (940.055 us; speedup 1.0000x reference)
//
#include <hip/hip_runtime.h>

typedef __bf16 bf16;
typedef __attribute__((ext_vector_type(8))) __bf16 bf16x8;
typedef __attribute__((ext_vector_type(4))) __bf16 bf16x4;
typedef __attribute__((ext_vector_type(4))) float f32x4;

#define MFMA16(A, Bf, Cf) __builtin_amdgcn_mfma_f32_16x16x32_bf16((A), (Bf), (Cf), 0, 0, 0)

namespace {
constexpr int kB = 2048;
constexpr int kN = 64;
constexpr int kC = 256;
constexpr int kH = 8;
constexpr float kScale = 0.17677669529663687f;  // 1/sqrt(32)
constexpr size_t kOut0 = (size_t)kB * kN * kC;  // 33,554,432 floats (out), attn follows
// ws layout (bytes)
constexpr size_t kWqkvOff = 0;         // bf16 [768][256]
constexpr size_t kWprojOff = 393216;   // bf16 [256][256]
constexpr size_t kBiasOff = 524288;    // f32  [8][64][64]
}

// ---- prep: fp32->bf16 weights + materialize bias[h][i][j] -------------------
__global__ void prep_kernel(const float* __restrict__ qkv_w,
                            const float* __restrict__ proj_w,
                            const float* __restrict__ bias_table,
                            const int* __restrict__ rel_idx,
                            bf16* __restrict__ qkv_wb,
                            bf16* __restrict__ proj_wb,
                            float* __restrict__ biasf) {
  int t = blockIdx.x * 256 + threadIdx.x;
  if (t < 196608) {
    qkv_wb[t] = (bf16)qkv_w[t];
  } else if (t < 262144) {
    int u = t - 196608;
    proj_wb[u] = (bf16)proj_w[u];
  } else if (t < 294912) {
    int u = t - 262144;          // u = h*4096 + i*64 + j
    int h = u >> 12;
    int ij = u & 4095;
    biasf[u] = bias_table[rel_idx[ij] * 8 + h];
  }
}

// ---- fused windowed attention: 1 block = 1 window, 4 waves ------------------
// MFMA 16x16x32 bf16 layouts (measured, guide §3):
//   A: lane holds A[m=lane&15][k=quad*8+j]   (one ds_read_b128)
//   B: lane holds B[k=quad*8+j][n=lane&15]
//   D: lane holds D[row=quad*4+r][col=lane&15]
__launch_bounds__(256, 2)
__global__ void attn_kernel(const float* __restrict__ x,
                            const float* __restrict__ qkv_b,
                            const float* __restrict__ proj_b,
                            const bf16* __restrict__ qkv_wb,
                            const bf16* __restrict__ proj_wb,
                            const float* __restrict__ biasf,
                            float* __restrict__ out,
                            float* __restrict__ attn_out) {
  // pads chosen so b128 row strides hit only free 2-way bank aliasing
  __shared__ __align__(16) bf16 xb[64 * 264];     // x tile, bf16, stride 264
  __shared__ __align__(16) bf16 qk[2 * 64 * 40];  // qh | kh ; P[64][72] aliases both
  __shared__ __align__(16) bf16 vT[32 * 72];      // v transposed [d][token]
  __shared__ __align__(16) bf16 ohs[4 * 16 * 40]; // per-wave O_h staging [16][40]

  const int t = threadIdx.x;
  const int wave = t >> 6;
  const int lane = t & 63;
  const int l16 = lane & 15;
  const int quad = lane >> 4;
  const int b = blockIdx.x;
  const int mrow = wave * 16 + l16;  // A-operand row for this wave's M-tile

  bf16* qh = qk;
  bf16* kh = qk + 64 * 40;
  bf16* Pb = qk;  // [64][72], overwrites qh/kh after S is consumed

  const f32x4 fzero = {0.f, 0.f, 0.f, 0.f};

  // ---- stage x -> LDS bf16 (coalesced float4 loads) ----
  {
    const f32x4* xv = (const f32x4*)(x + (size_t)b * (kN * kC));
#pragma unroll
    for (int i = 0; i < 16; ++i) {
      int g4 = i * 256 + t;        // 0..4095 float4s
      f32x4 v = xv[g4];
      int row = g4 >> 6;
      int c4 = (g4 & 63) << 2;
      bf16x4 w;
      w.x = (bf16)v.x; w.y = (bf16)v.y; w.z = (bf16)v.z; w.w = (bf16)v.w;
      *(bf16x4*)&xb[row * 264 + c4] = w;
    }
  }
  __syncthreads();

  // persistent proj accumulators: out tile [16 rows (wave)] x [256]
  f32x4 pacc[16];
#pragma unroll
  for (int i = 0; i < 16; ++i) pacc[i] = fzero;

  for (int h = 0; h < kH; ++h) {
    // ---- QKV GEMM for head h: 64 x 96 (q|k|v), K=256 ----
    bf16x8 afr[8];
#pragma unroll
    for (int kt = 0; kt < 8; ++kt)
      afr[kt] = *(const bf16x8*)&xb[mrow * 264 + kt * 32 + quad * 8];

    f32x4 acc[6];
#pragma unroll
    for (int nt = 0; nt < 6; ++nt) acc[nt] = fzero;
#pragma unroll
    for (int nt = 0; nt < 6; ++nt) {
      int wrow = (nt < 2) ? (h * 32 + nt * 16 + l16)
               : (nt < 4) ? (256 + h * 32 + (nt - 2) * 16 + l16)
                          : (512 + h * 32 + (nt - 4) * 16 + l16);
      const bf16* wp = qkv_wb + wrow * 256 + quad * 8;
      bf16x8 bfr[8];
#pragma unroll
      for (int kt = 0; kt < 8; ++kt) bfr[kt] = *(const bf16x8*)&wp[kt * 32];
#pragma unroll
      for (int kt = 0; kt < 8; ++kt) acc[nt] = MFMA16(afr[kt], bfr[kt], acc[nt]);
    }

    // barrier: all waves finished prev head's P/vT reads before we overwrite
    __syncthreads();

    // ---- epilogue: +bias, scale q, write q/k natural, v transposed ----
#pragma unroll
    for (int nt = 0; nt < 6; ++nt) {
      int col = (nt & 1) * 16 + l16;
      float qb = qkv_b[((nt < 2) ? 0 : (nt < 4) ? 256 : 512) + h * 32 + col];
#pragma unroll
      for (int r = 0; r < 4; ++r) {
        int row = wave * 16 + quad * 4 + r;
        float val = acc[nt][r] + qb;
        if (nt < 2)       qh[row * 40 + col] = (bf16)(val * kScale);
        else if (nt < 4)  kh[row * 40 + col] = (bf16)val;
        else              vT[col * 72 + row] = (bf16)val;
      }
    }
    __syncthreads();

    // ---- S = q @ k^T + bias (wave w owns rows [16w,16w+16)) ----
    float bs[4][4];
    const float* bp = biasf + h * 4096;
#pragma unroll
    for (int ct = 0; ct < 4; ++ct)
#pragma unroll
      for (int r = 0; r < 4; ++r)
        bs[ct][r] = bp[(wave * 16 + quad * 4 + r) * 64 + ct * 16 + l16];

    bf16x8 aS = *(const bf16x8*)&qh[mrow * 40 + quad * 8];
    f32x4 s[4];
#pragma unroll
    for (int ct = 0; ct < 4; ++ct) {
      bf16x8 bS = *(const bf16x8*)&kh[(ct * 16 + l16) * 40 + quad * 8];
      s[ct] = MFMA16(aS, bS, fzero);
    }
#pragma unroll
    for (int ct = 0; ct < 4; ++ct)
#pragma unroll
      for (int r = 0; r < 4; ++r) s[ct][r] += bs[ct][r];

    // ---- softmax over j (row lives in one 16-lane quad group + 4 regs) ----
#pragma unroll
    for (int r = 0; r < 4; ++r) {
      float m = fmaxf(fmaxf(s[0][r], s[1][r]), fmaxf(s[2][r], s[3][r]));
#pragma unroll
      for (int off = 8; off; off >>= 1) m = fmaxf(m, __shfl_xor(m, off));
      float e0 = __expf(s[0][r] - m);
      float e1 = __expf(s[1][r] - m);
      float e2 = __expf(s[2][r] - m);
      float e3 = __expf(s[3][r] - m);
      float sum = (e0 + e1) + (e2 + e3);
#pragma unroll
      for (int off = 8; off; off >>= 1) sum += __shfl_xor(sum, off);
      float is = 1.0f / sum;
      s[0][r] = e0 * is; s[1][r] = e1 * is; s[2][r] = e2 * is; s[3][r] = e3 * is;
    }

    // barrier: every wave done reading qh/kh before P overwrites them
    __syncthreads();

    // ---- write attn (fp32, global) + P (bf16, LDS A-layout source) ----
    float* ao = attn_out + ((size_t)(b * kH + h) << 12);
#pragma unroll
    for (int ct = 0; ct < 4; ++ct)
#pragma unroll
      for (int r = 0; r < 4; ++r) {
        int i = wave * 16 + quad * 4 + r;
        int j = ct * 16 + l16;
        float pv = s[ct][r];
        ao[i * 64 + j] = pv;
        Pb[i * 72 + j] = (bf16)pv;
      }
    // P rows for this wave's PV A-frags were written by this wave itself:
    // within-wave lgkmcnt ordering suffices, no barrier.

    // ---- O_h = P @ V (K=64 -> 2 MFMA steps; n = d in [0,32)) ----
    f32x4 o[2];
    o[0] = fzero; o[1] = fzero;
#pragma unroll
    for (int ks = 0; ks < 2; ++ks) {
      bf16x8 aP = *(const bf16x8*)&Pb[mrow * 72 + ks * 32 + quad * 8];
#pragma unroll
      for (int nt = 0; nt < 2; ++nt) {
        bf16x8 bV = *(const bf16x8*)&vT[(nt * 16 + l16) * 72 + ks * 32 + quad * 8];
        o[nt] = MFMA16(aP, bV, o[nt]);
      }
    }

    // ---- stage O_h (wave-private) and fold into proj accumulators ----
    bf16* oh = ohs + wave * (16 * 40);
#pragma unroll
    for (int nt = 0; nt < 2; ++nt)
#pragma unroll
      for (int r = 0; r < 4; ++r)
        oh[(quad * 4 + r) * 40 + nt * 16 + l16] = (bf16)o[nt][r];

    bf16x8 aO = *(const bf16x8*)&oh[l16 * 40 + quad * 8];
#pragma unroll
    for (int nt = 0; nt < 16; ++nt) {
      bf16x8 bW = *(const bf16x8*)&proj_wb[(nt * 16 + l16) * 256 + h * 32 + quad * 8];
      pacc[nt] = MFMA16(aO, bW, pacc[nt]);
    }
  }

  // ---- final: out = pacc + proj_b ----
  float* op = out + (size_t)b * (kN * kC);
#pragma unroll
  for (int nt = 0; nt < 16; ++nt) {
    float pb = proj_b[nt * 16 + l16];
#pragma unroll
    for (int r = 0; r < 4; ++r) {
      int i = wave * 16 + quad * 4 + r;
      op[i * 256 + nt * 16 + l16] = pacc[nt][r] + pb;
    }
  }
}

extern "C" void kernel_launch(void* const* d_in, const int* in_sizes, int n_in,
                              void* d_out, int out_size, void* d_ws, size_t ws_size,
                              hipStream_t stream) {
  const float* x          = (const float*)d_in[0];
  const float* qkv_w      = (const float*)d_in[1];
  const float* qkv_b      = (const float*)d_in[2];
  const float* proj_w     = (const float*)d_in[3];
  const float* proj_b     = (const float*)d_in[4];
  const float* bias_table = (const float*)d_in[5];
  const int*   rel_idx    = (const int*)d_in[6];

  bf16*  qkv_wb = (bf16*)((char*)d_ws + kWqkvOff);
  bf16*  proj_wb = (bf16*)((char*)d_ws + kWprojOff);
  float* biasf  = (float*)((char*)d_ws + kBiasOff);

  float* out      = (float*)d_out;
  float* attn_out = out + kOut0;

  prep_kernel<<<1152, 256, 0, stream>>>(qkv_w, proj_w, bias_table, rel_idx,
                                        qkv_wb, proj_wb, biasf);
  attn_kernel<<<kB, 256, 0, stream>>>(x, qkv_b, proj_b, qkv_wb, proj_wb, biasf,
                                      out, attn_out);
}